// Round 1
// baseline (195.237 us; speedup 1.0000x reference)
//
#include <hip/hip_runtime.h>
#include <math.h>

#define Bn 32
#define Pn 32768
#define On 32
#define TPB 256
#define PPT 2                 // priors per thread in matchB
#define BP  (TPB * PPT)       // priors per matchB block = 512
#define AG 8                  // targets per matchA block
#define AC 1024               // priors per matchA block (= 256 threads * 4)

// d_ws layout:
// [0,     8192)  u64   bpm[Bn*On]   packed (iou_bits<<32 | (Pn-1-p)) per (b,o)
// [8192,  8320)  int   num_pos[Bn]
// [8320,  8324)  float loss_l_total
// [8324,  8328)  float ce_total
// [8328,  8332)  int   np_total
// [16384, 16384+4*Bn*Pn) float ce_mine[Bn*Pn]

__device__ __forceinline__ unsigned long long shfl_down_u64(unsigned long long v, int off) {
    unsigned lo = (unsigned)(v & 0xFFFFFFFFull);
    unsigned hi = (unsigned)(v >> 32);
    lo = __shfl_down(lo, off, 64);
    hi = __shfl_down(hi, off, 64);
    return ((unsigned long long)hi << 32) | lo;
}

// ---------------- Phase A: per-(b,o) argmax_p IoU ----------------
// grid (Bn*On/AG, Pn/AC), 256 threads. Each block: 8 targets (LDS) vs
// 1024 priors (4/thread in registers). Per-target wave shuffle-max of
// packed key, LDS u64 atomicMax across waves, 8 global atomics/block.
__global__ __launch_bounds__(256) void matchA(const float4* __restrict__ priors,
                                              const float* __restrict__ targets,
                                              unsigned long long* __restrict__ bpm) {
    int g    = blockIdx.x;            // target group
    int base = blockIdx.y * AC;       // prior chunk
    int tid  = threadIdx.x;

    __shared__ float4 tb[AG];
    __shared__ float  ta[AG];
    __shared__ unsigned long long sbest[AG];

    if (tid < AG) {
        const float* t = targets + (size_t)(g * AG + tid) * 5;
        float x1 = t[0], y1 = t[1], x2 = t[2], y2 = t[3];
        tb[tid] = make_float4(x1, y1, x2, y2);
        ta[tid] = (x2 - x1) * (y2 - y1);
        sbest[tid] = 0ull;
    }
    __syncthreads();

    float px1[4], py1[4], px2[4], py2[4], ab[4];
#pragma unroll
    for (int j = 0; j < 4; j++) {
        float4 pr = priors[base + tid + 256 * j];
        px1[j] = pr.x - pr.z * 0.5f; py1[j] = pr.y - pr.w * 0.5f;
        px2[j] = pr.x + pr.z * 0.5f; py2[j] = pr.y + pr.w * 0.5f;
        ab[j]  = (px2[j] - px1[j]) * (py2[j] - py1[j]);
    }

#pragma unroll
    for (int o = 0; o < AG; o++) {
        float4 tt = tb[o];
        float  a  = ta[o];
        float bI = 0.f, bU = 1.f;
        int   bj = 0;
#pragma unroll
        for (int j = 0; j < 4; j++) {
            float ix1 = fmaxf(tt.x, px1[j]), iy1 = fmaxf(tt.y, py1[j]);
            float ix2 = fminf(tt.z, px2[j]), iy2 = fminf(tt.w, py2[j]);
            float iw = fmaxf(ix2 - ix1, 0.f), ih = fmaxf(iy2 - iy1, 0.f);
            float I = iw * ih;
            float U = a + ab[j] - I;
            if (I * bU > bI * U) { bI = I; bU = U; bj = j; }
        }
        int p = base + tid + 256 * bj;
        float iou = bI / bU;                 // IEEE divide: same key rounding as reference
        unsigned long long key = ((unsigned long long)__float_as_uint(iou) << 32)
                               | (unsigned)(Pn - 1 - p);
#pragma unroll
        for (int off = 32; off > 0; off >>= 1) {
            unsigned long long other = shfl_down_u64(key, off);
            if (other > key) key = other;
        }
        if ((tid & 63) == 0) atomicMax(&sbest[o], key);
    }
    __syncthreads();
    if (tid < AG) atomicMax(&bpm[g * AG + tid], sbest[tid]);
}

// ------- Phase B: per-prior matching, loc loss, CE, ce_mine -------
// grid (Pn/BP, Bn), 256 threads, PPT=2 priors/thread (strided by 256).
// 2048 blocks -> 8192 waves -> 32 waves/CU theoretical occupancy.
__global__ __launch_bounds__(256) void matchB(const float* __restrict__ loc,
                                              const float2* __restrict__ conf2,
                                              const float4* __restrict__ priors,
                                              const float* __restrict__ targets,
                                              const unsigned long long* __restrict__ bpm,
                                              float* __restrict__ ce_mine,
                                              int* __restrict__ num_pos,
                                              float* __restrict__ loss_l_t,
                                              float* __restrict__ ce_t,
                                              int* __restrict__ np_tot) {
    int b = blockIdx.y;
    int base = blockIdx.x * BP;
    int tid = threadIdx.x;

    __shared__ float4 tb[On];
    __shared__ float  ta[On], lb[On];
    __shared__ int    forced[BP];    // truth index forcing this prior, else -1
    __shared__ float  sred[12];

#pragma unroll
    for (int j = 0; j < PPT; j++) forced[tid + 256 * j] = -1;
    int sp = -1;
    if (tid < On) {
        const float* t = targets + ((size_t)b * On + tid) * 5;
        float x1 = t[0], y1 = t[1], x2 = t[2], y2 = t[3];
        tb[tid] = make_float4(x1, y1, x2, y2);
        ta[tid] = (x2 - x1) * (y2 - y1);
        lb[tid] = t[4];
        sp = Pn - 1 - (int)(bpm[b * On + tid] & 0xFFFFFFFFull);
    }
    __syncthreads();            // forced[] init complete
    if (tid < On && sp >= base && sp < base + BP)
        atomicMax(&forced[sp - base], tid);   // duplicate bpi: max o == numpy last-write
    __syncthreads();

    float px1[PPT], py1[PPT], px2[PPT], py2[PPT], ab[PPT], pcx[PPT], pcy[PPT], pw[PPT], ph[PPT];
#pragma unroll
    for (int j = 0; j < PPT; j++) {
        float4 pr = priors[base + tid + 256 * j];
        pcx[j] = pr.x; pcy[j] = pr.y; pw[j] = pr.z; ph[j] = pr.w;
        px1[j] = pr.x - pr.z * 0.5f; py1[j] = pr.y - pr.w * 0.5f;
        px2[j] = pr.x + pr.z * 0.5f; py2[j] = pr.y + pr.w * 0.5f;
        ab[j]  = (px2[j] - px1[j]) * (py2[j] - py1[j]);
    }

    float bI[PPT] = {0.f, 0.f};
    float bU[PPT] = {1.f, 1.f};
    int   bx[PPT] = {0, 0};
#pragma unroll 4
    for (int o = 0; o < On; o++) {
        float4 tt = tb[o];
        float  a  = ta[o];
#pragma unroll
        for (int j = 0; j < PPT; j++) {
            float ix1 = fmaxf(tt.x, px1[j]), iy1 = fmaxf(tt.y, py1[j]);
            float ix2 = fminf(tt.z, px2[j]), iy2 = fminf(tt.w, py2[j]);
            float iw = fmaxf(ix2 - ix1, 0.f), ih = fmaxf(iy2 - iy1, 0.f);
            float I = iw * ih;
            float U = a + ab[j] - I;
            if (I * bU[j] > bI[j] * U) { bI[j] = I; bU[j] = U; bx[j] = o; }
        }
    }

    float ll_s = 0.f, pce_s = 0.f, cnt_s = 0.f;
#pragma unroll
    for (int j = 0; j < PPT; j++) {
        int p = base + tid + 256 * j;
        int fo = forced[tid + 256 * j];
        int bidx = (fo >= 0) ? fo : bx[j];
        int cf;
        if (fo >= 0)                      cf = (int)lb[bidx];
        else if (bI[j] >= 0.5f * bU[j])   cf = (int)lb[bidx];
        else                              cf = 0;
        bool pos = cf > 0;

        if (pos) {
            float4 tt = tb[bidx];
            float g0 = ((tt.x + tt.z) * 0.5f - pcx[j]) / (0.1f * pw[j]);
            float g1 = ((tt.y + tt.w) * 0.5f - pcy[j]) / (0.1f * ph[j]);
            float g2 = __logf((tt.z - tt.x) / pw[j]) * 5.0f;
            float g3 = __logf((tt.w - tt.y) / ph[j]) * 5.0f;
            const float* lp = loc + ((size_t)b * Pn + p) * 3;
            float q0 = lp[0], q1 = lp[1], q2 = lp[2];
            float dd[4] = { q0 - g0, q1 - g1, q2 - g2, q2 - g3 };
#pragma unroll
            for (int i = 0; i < 4; i++) {
                float ad = fabsf(dd[i]);
                ll_s += (ad < 1.f) ? 0.5f * dd[i] * dd[i] : (ad - 0.5f);
            }
            cnt_s += 1.f;
        }

        float2 cc = conf2[(size_t)b * Pn + p];
        float m = fmaxf(cc.x, cc.y);
        float lse = m + __logf(__expf(cc.x - m) + __expf(cc.y - m));
        float ce = lse - (cf ? cc.y : cc.x);       // >= 0
        if (pos) { pce_s += ce; ce = 0.f; }
        ce_mine[(size_t)b * Pn + p] = fmaxf(ce, 0.f);
    }

    // fused 3-value block reduce
#pragma unroll
    for (int off = 32; off > 0; off >>= 1) {
        ll_s  += __shfl_down(ll_s,  off, 64);
        pce_s += __shfl_down(pce_s, off, 64);
        cnt_s += __shfl_down(cnt_s, off, 64);
    }
    int lane = tid & 63, wv = tid >> 6;
    if (lane == 0) { sred[wv * 3] = ll_s; sred[wv * 3 + 1] = pce_s; sred[wv * 3 + 2] = cnt_s; }
    __syncthreads();
    if (tid == 0) {
        float llr = 0, pcer = 0, cntr = 0;
        for (int w = 0; w < 4; w++) { llr += sred[w*3]; pcer += sred[w*3+1]; cntr += sred[w*3+2]; }
        if (llr != 0.f)  atomicAdd(loss_l_t, llr);
        if (pcer != 0.f) atomicAdd(ce_t, pcer);
        int c = (int)cntr;
        if (c) { atomicAdd(&num_pos[b], c); atomicAdd(np_tot, c); }
    }
}

// ---- Phase C: exact top-k sum via 3-round radix histogram select ----
// One block per batch, 1024 threads, 32 values/thread in VGPRs.
// Rounds on uint bits (nonneg floats monotone): 11 + 11 + 9 bits.
// Invariant: tau in [LO, LO + nb<<shift), AB = count(u >= bracket top) < k.
__global__ __launch_bounds__(1024) void topk(const float* __restrict__ ce_mine,
                                             const int* __restrict__ num_pos,
                                             float* __restrict__ ce_t) {
    int b = blockIdx.x, tid = threadIdx.x;
    const float4* v4 = (const float4*)(ce_mine + (size_t)b * Pn);
    float4 r[8];
#pragma unroll
    for (int i = 0; i < 8; i++) r[i] = v4[i * 1024 + tid];

    int k = 3 * num_pos[b];
    if (k > Pn - 1) k = Pn - 1;
    if (k <= 0) return;                       // uniform across block

    __shared__ int hist[4][2048];             // 4-way sub-hist (per 4-wave group)
    __shared__ int wavetot[16];
    __shared__ int waveabove[16];
    __shared__ unsigned long long wcand[16];
    __shared__ unsigned s_lo;
    __shared__ int s_ab;
    __shared__ float ssum[16];
    __shared__ int   scnt[16];

    int lane = tid & 63, wv = tid >> 6;
    unsigned LO = 0u;
    int AB = 0;

    const int shifts[3] = {20, 9, 0};
    const int nbs[3]    = {2048, 2048, 512};

#pragma unroll
    for (int rd = 0; rd < 3; rd++) {
        int shift = shifts[rd], nb = nbs[rd];
        // zero all 4 sub-hists
        int* hf = &hist[0][0];
        for (int i = tid; i < 4 * 2048; i += 1024) hf[i] = 0;
        __syncthreads();
        // count in-bracket values
        int* myh = hist[wv >> 2];
#pragma unroll
        for (int i = 0; i < 8; i++) {
            float4 rv = r[i];
            float vals[4] = {rv.x, rv.y, rv.z, rv.w};
#pragma unroll
            for (int q = 0; q < 4; q++) {
                unsigned u = __float_as_uint(vals[q]);
                unsigned bin = (u - LO) >> shift;        // underflow -> huge -> skipped
                if (bin < (unsigned)nb) atomicAdd(&myh[bin], 1);
            }
        }
        __syncthreads();
        // thread owns bins 2*tid, 2*tid+1 (wave w owns contiguous [128w,128w+128))
        int c0 = hist[0][2*tid] + hist[1][2*tid] + hist[2][2*tid] + hist[3][2*tid];
        int c1 = hist[0][2*tid+1] + hist[1][2*tid+1] + hist[2][2*tid+1] + hist[3][2*tid+1];
        int local = c0 + c1;
        // wave inclusive suffix scan (Hillis-Steele, masked shfl)
        int suf = local;
#pragma unroll
        for (int off = 1; off < 64; off <<= 1) {
            int src = lane + off;
            int o = __shfl(suf, src & 63, 64);
            suf += (src < 64) ? o : 0;
        }
        if (lane == 0) wavetot[wv] = suf;
        __syncthreads();
        if (tid == 0) {
            int acc = AB;                     // count(u >= bracket top)
            for (int w = 15; w >= 0; w--) { waveabove[w] = acc; acc += wavetot[w]; }
        }
        __syncthreads();
        int S0 = waveabove[wv] + suf;         // count(u >= LO + (2*tid)<<shift)
        int S1 = S0 - c0;                     // count(u >= LO + (2*tid+1)<<shift)
        int cand = -1; unsigned nab = 0;
        if (S0 >= k) { cand = 2*tid;     nab = (unsigned)(S0 - c0); }
        if (S1 >= k) { cand = 2*tid + 1; nab = (unsigned)(S1 - c1); }
        unsigned long long pk = ((unsigned long long)(unsigned)(cand + 1) << 32) | nab;
#pragma unroll
        for (int off = 32; off > 0; off >>= 1) {
            unsigned long long o = shfl_down_u64(pk, off);
            if (o > pk) pk = o;
        }
        if (lane == 0) wcand[wv] = pk;
        __syncthreads();
        if (tid == 0) {
            unsigned long long best = 0;
            for (int w = 0; w < 16; w++) if (wcand[w] > best) best = wcand[w];
            int ci = (int)(best >> 32) - 1;   // S_0 >= k guarantees ci >= 0
            s_lo = LO + ((unsigned)ci << shift);
            s_ab = (int)(best & 0xFFFFFFFFu);
        }
        __syncthreads();
        LO = s_lo; AB = s_ab;
    }
    // final bracket width 1: tau bits == LO; count(> tau) = AB < k <= count(>= tau)
    float tau = __uint_as_float(LO);
    float s = 0.f; int c = 0;
#pragma unroll
    for (int i = 0; i < 8; i++) {
        if (r[i].x > tau) { s += r[i].x; c++; }
        if (r[i].y > tau) { s += r[i].y; c++; }
        if (r[i].z > tau) { s += r[i].z; c++; }
        if (r[i].w > tau) { s += r[i].w; c++; }
    }
#pragma unroll
    for (int off = 32; off > 0; off >>= 1) {
        s += __shfl_down(s, off, 64);
        c += __shfl_down(c, off, 64);
    }
    if (lane == 0) { ssum[wv] = s; scnt[wv] = c; }
    __syncthreads();
    if (tid == 0) {
        float st = 0.f; int ct = 0;
        for (int w = 0; w < 16; w++) { st += ssum[w]; ct += scnt[w]; }
        atomicAdd(ce_t, st + (float)(k - ct) * tau);   // ties at tau, tie-agnostic exact
    }
}

// ---------------- Phase D: finalize ----------------
__global__ void finalize(const float* __restrict__ loss_l_t,
                         const float* __restrict__ ce_t,
                         const int* __restrict__ np_tot,
                         float* __restrict__ out) {
    float N = (float)(*np_tot);
    out[0] = *loss_l_t / N;
    out[1] = *ce_t / N;
}

extern "C" void kernel_launch(void* const* d_in, const int* in_sizes, int n_in,
                              void* d_out, int out_size, void* d_ws, size_t ws_size,
                              hipStream_t stream) {
    const float* loc     = (const float*)d_in[0];  // (B,P,3)
    const float* conf    = (const float*)d_in[1];  // (B,P,2)
    const float* priors  = (const float*)d_in[2];  // (P,4)
    const float* targets = (const float*)d_in[3];  // (B,O,5)
    float* out = (float*)d_out;

    char* ws = (char*)d_ws;
    unsigned long long* bpm = (unsigned long long*)ws;
    int*   num_pos  = (int*)(ws + 8192);
    float* loss_l_t = (float*)(ws + 8320);
    float* ce_t     = (float*)(ws + 8324);
    int*   np_tot   = (int*)(ws + 8328);
    float* ce_mine  = (float*)(ws + 16384);

    hipMemsetAsync(ws, 0, 16384, stream);

    hipLaunchKernelGGL(matchA, dim3((Bn * On) / AG, Pn / AC), dim3(256), 0, stream,
                       (const float4*)priors, targets, bpm);
    hipLaunchKernelGGL(matchB, dim3(Pn / BP, Bn), dim3(256), 0, stream,
                       loc, (const float2*)conf, (const float4*)priors, targets, bpm,
                       ce_mine, num_pos, loss_l_t, ce_t, np_tot);
    hipLaunchKernelGGL(topk, dim3(Bn), dim3(1024), 0, stream, ce_mine, num_pos, ce_t);
    hipLaunchKernelGGL(finalize, dim3(1), dim3(1), 0, stream, loss_l_t, ce_t, np_tot, out);
}

// Round 2
// 157.720 us; speedup vs baseline: 1.2379x; 1.2379x over previous
//
#include <hip/hip_runtime.h>
#include <math.h>

#define Bn 32
#define Pn 32768
#define On 32
#define TPB 256
#define PPT 4                 // priors per thread in matchB
#define BP  (TPB * PPT)       // priors per matchB block = 1024
#define AG 8                  // targets per matchA block
#define AC 1024               // priors per matchA block (= 256 threads * 4)

// d_ws layout:
// [0,     8192)  u64   bpm[Bn*On]   packed (iou_bits<<32 | (Pn-1-p)) per (b,o)
// [8192,  8320)  int   num_pos[Bn]
// [8320,  8324)  float loss_l_total
// [8324,  8328)  float ce_total
// [8328,  8332)  int   np_total
// [8332,  8336)  uint  tick (topk completion ticket)
// [16384, 16384+4*Bn*Pn) float ce_mine[Bn*Pn]

__device__ __forceinline__ unsigned long long shfl_down_u64(unsigned long long v, int off) {
    unsigned lo = (unsigned)(v & 0xFFFFFFFFull);
    unsigned hi = (unsigned)(v >> 32);
    lo = __shfl_down(lo, off, 64);
    hi = __shfl_down(hi, off, 64);
    return ((unsigned long long)hi << 32) | lo;
}

// ---------------- Phase A: per-(b,o) argmax_p IoU ----------------
// grid (Bn*On/AG, Pn/AC), 256 threads. Each block: 8 targets (LDS) vs
// 1024 priors (4/thread in registers). Per-target wave shuffle-max of
// packed key, LDS u64 atomicMax across waves, 8 global atomics/block.
__global__ __launch_bounds__(256) void matchA(const float4* __restrict__ priors,
                                              const float* __restrict__ targets,
                                              unsigned long long* __restrict__ bpm) {
    int g    = blockIdx.x;            // target group
    int base = blockIdx.y * AC;       // prior chunk
    int tid  = threadIdx.x;

    __shared__ float4 tb[AG];
    __shared__ float  ta[AG];
    __shared__ unsigned long long sbest[AG];

    if (tid < AG) {
        const float* t = targets + (size_t)(g * AG + tid) * 5;
        float x1 = t[0], y1 = t[1], x2 = t[2], y2 = t[3];
        tb[tid] = make_float4(x1, y1, x2, y2);
        ta[tid] = (x2 - x1) * (y2 - y1);
        sbest[tid] = 0ull;
    }
    __syncthreads();

    float px1[4], py1[4], px2[4], py2[4], ab[4];
#pragma unroll
    for (int j = 0; j < 4; j++) {
        float4 pr = priors[base + tid + 256 * j];
        px1[j] = pr.x - pr.z * 0.5f; py1[j] = pr.y - pr.w * 0.5f;
        px2[j] = pr.x + pr.z * 0.5f; py2[j] = pr.y + pr.w * 0.5f;
        ab[j]  = (px2[j] - px1[j]) * (py2[j] - py1[j]);
    }

#pragma unroll
    for (int o = 0; o < AG; o++) {
        float4 tt = tb[o];
        float  a  = ta[o];
        float bI = 0.f, bU = 1.f;
        int   bj = 0;
#pragma unroll
        for (int j = 0; j < 4; j++) {
            float ix1 = fmaxf(tt.x, px1[j]), iy1 = fmaxf(tt.y, py1[j]);
            float ix2 = fminf(tt.z, px2[j]), iy2 = fminf(tt.w, py2[j]);
            float iw = fmaxf(ix2 - ix1, 0.f), ih = fmaxf(iy2 - iy1, 0.f);
            float I = iw * ih;
            float U = a + ab[j] - I;
            if (I * bU > bI * U) { bI = I; bU = U; bj = j; }
        }
        int p = base + tid + 256 * bj;
        float iou = bI / bU;                 // IEEE divide: same key rounding as reference
        unsigned long long key = ((unsigned long long)__float_as_uint(iou) << 32)
                               | (unsigned)(Pn - 1 - p);
#pragma unroll
        for (int off = 32; off > 0; off >>= 1) {
            unsigned long long other = shfl_down_u64(key, off);
            if (other > key) key = other;
        }
        if ((tid & 63) == 0) atomicMax(&sbest[o], key);
    }
    __syncthreads();
    if (tid < AG) atomicMax(&bpm[g * AG + tid], sbest[tid]);
}

// ------- Phase B: per-prior matching, loc loss, CE, ce_mine -------
// grid (Pn/BP, Bn), 256 threads, PPT=4 priors/thread (strided by 256).
// o-loop split into two 16-long chains per prior (8 independent chains)
// to halve the loop-carried cndmask critical path; conf2 prefetched at
// entry so the HBM miss drains under the o-loop.
__global__ __launch_bounds__(256) void matchB(const float* __restrict__ loc,
                                              const float2* __restrict__ conf2,
                                              const float4* __restrict__ priors,
                                              const float* __restrict__ targets,
                                              const unsigned long long* __restrict__ bpm,
                                              float* __restrict__ ce_mine,
                                              int* __restrict__ num_pos,
                                              float* __restrict__ loss_l_t,
                                              float* __restrict__ ce_t,
                                              int* __restrict__ np_tot) {
    int b = blockIdx.y;
    int base = blockIdx.x * BP;
    int tid = threadIdx.x;

    // prefetch conf2 first thing: latency hides under the whole o-loop
    float2 cc[PPT];
#pragma unroll
    for (int j = 0; j < PPT; j++) cc[j] = conf2[(size_t)b * Pn + base + tid + 256 * j];

    __shared__ float4 tb[On];
    __shared__ float  ta[On], lb[On];
    __shared__ int    forced[BP];    // truth index forcing this prior, else -1
    __shared__ float  sred[12];

#pragma unroll
    for (int j = 0; j < PPT; j++) forced[tid + 256 * j] = -1;
    int sp = -1;
    if (tid < On) {
        const float* t = targets + ((size_t)b * On + tid) * 5;
        float x1 = t[0], y1 = t[1], x2 = t[2], y2 = t[3];
        tb[tid] = make_float4(x1, y1, x2, y2);
        ta[tid] = (x2 - x1) * (y2 - y1);
        lb[tid] = t[4];
        sp = Pn - 1 - (int)(bpm[b * On + tid] & 0xFFFFFFFFull);
    }
    __syncthreads();            // forced[] init complete
    if (tid < On && sp >= base && sp < base + BP)
        atomicMax(&forced[sp - base], tid);   // duplicate bpi: max o == numpy last-write
    __syncthreads();

    float px1[PPT], py1[PPT], px2[PPT], py2[PPT], ab[PPT], pcx[PPT], pcy[PPT], pw[PPT], ph[PPT];
#pragma unroll
    for (int j = 0; j < PPT; j++) {
        float4 pr = priors[base + tid + 256 * j];
        pcx[j] = pr.x; pcy[j] = pr.y; pw[j] = pr.z; ph[j] = pr.w;
        px1[j] = pr.x - pr.z * 0.5f; py1[j] = pr.y - pr.w * 0.5f;
        px2[j] = pr.x + pr.z * 0.5f; py2[j] = pr.y + pr.w * 0.5f;
        ab[j]  = (px2[j] - px1[j]) * (py2[j] - py1[j]);
    }

    // two independent 16-long chains per prior (h = o/16), merged after.
    float bIc[PPT][2], bUc[PPT][2];
    int   bxc[PPT][2];
#pragma unroll
    for (int j = 0; j < PPT; j++)
#pragma unroll
        for (int h = 0; h < 2; h++) { bIc[j][h] = 0.f; bUc[j][h] = 1.f; bxc[j][h] = h * 16; }

#pragma unroll 2
    for (int o16 = 0; o16 < 16; o16++) {
#pragma unroll
        for (int h = 0; h < 2; h++) {
            int o = h * 16 + o16;
            float4 tt = tb[o];
            float  a  = ta[o];
#pragma unroll
            for (int j = 0; j < PPT; j++) {
                float ix1 = fmaxf(tt.x, px1[j]), iy1 = fmaxf(tt.y, py1[j]);
                float ix2 = fminf(tt.z, px2[j]), iy2 = fminf(tt.w, py2[j]);
                float iw = fmaxf(ix2 - ix1, 0.f), ih = fmaxf(iy2 - iy1, 0.f);
                float I = iw * ih;
                float U = a + ab[j] - I;
                if (I * bUc[j][h] > bIc[j][h] * U) { bIc[j][h] = I; bUc[j][h] = U; bxc[j][h] = o; }
            }
        }
    }
    // merge: chain1 wins only if strictly greater -> earliest-o tie semantics kept
    float bI[PPT], bU[PPT];
    int   bx[PPT];
#pragma unroll
    for (int j = 0; j < PPT; j++) {
        bI[j] = bIc[j][0]; bU[j] = bUc[j][0]; bx[j] = bxc[j][0];
        if (bIc[j][1] * bU[j] > bI[j] * bUc[j][1]) { bI[j] = bIc[j][1]; bU[j] = bUc[j][1]; bx[j] = bxc[j][1]; }
    }

    float ll_s = 0.f, pce_s = 0.f, cnt_s = 0.f;
#pragma unroll
    for (int j = 0; j < PPT; j++) {
        int p = base + tid + 256 * j;
        int fo = forced[tid + 256 * j];
        int bidx = (fo >= 0) ? fo : bx[j];
        int cf;
        if (fo >= 0)                      cf = (int)lb[bidx];
        else if (bI[j] >= 0.5f * bU[j])   cf = (int)lb[bidx];
        else                              cf = 0;
        bool pos = cf > 0;

        if (pos) {
            float4 tt = tb[bidx];
            float g0 = ((tt.x + tt.z) * 0.5f - pcx[j]) / (0.1f * pw[j]);
            float g1 = ((tt.y + tt.w) * 0.5f - pcy[j]) / (0.1f * ph[j]);
            float g2 = __logf((tt.z - tt.x) / pw[j]) * 5.0f;
            float g3 = __logf((tt.w - tt.y) / ph[j]) * 5.0f;
            const float* lp = loc + ((size_t)b * Pn + p) * 3;
            float q0 = lp[0], q1 = lp[1], q2 = lp[2];
            float dd[4] = { q0 - g0, q1 - g1, q2 - g2, q2 - g3 };
#pragma unroll
            for (int i = 0; i < 4; i++) {
                float ad = fabsf(dd[i]);
                ll_s += (ad < 1.f) ? 0.5f * dd[i] * dd[i] : (ad - 0.5f);
            }
            cnt_s += 1.f;
        }

        float m = fmaxf(cc[j].x, cc[j].y);
        float lse = m + __logf(__expf(cc[j].x - m) + __expf(cc[j].y - m));
        float ce = lse - (cf ? cc[j].y : cc[j].x);     // >= 0
        if (pos) { pce_s += ce; ce = 0.f; }
        ce_mine[(size_t)b * Pn + p] = fmaxf(ce, 0.f);
    }

    // fused 3-value block reduce
#pragma unroll
    for (int off = 32; off > 0; off >>= 1) {
        ll_s  += __shfl_down(ll_s,  off, 64);
        pce_s += __shfl_down(pce_s, off, 64);
        cnt_s += __shfl_down(cnt_s, off, 64);
    }
    int lane = tid & 63, wv = tid >> 6;
    if (lane == 0) { sred[wv * 3] = ll_s; sred[wv * 3 + 1] = pce_s; sred[wv * 3 + 2] = cnt_s; }
    __syncthreads();
    if (tid == 0) {
        float llr = 0, pcer = 0, cntr = 0;
        for (int w = 0; w < 4; w++) { llr += sred[w*3]; pcer += sred[w*3+1]; cntr += sred[w*3+2]; }
        if (llr != 0.f)  atomicAdd(loss_l_t, llr);
        if (pcer != 0.f) atomicAdd(ce_t, pcer);
        int c = (int)cntr;
        if (c) { atomicAdd(&num_pos[b], c); atomicAdd(np_tot, c); }
    }
}

// ---- Phase C: exact top-k sum via 3-round radix histogram select ----
// One block per batch, 1024 threads, 32 values/thread in VGPRs.
// Rounds on uint bits (nonneg floats monotone): 11 + 11 + 9 bits.
// Last block to finish also finalizes the output (ticket counter).
__global__ __launch_bounds__(1024) void topk(const float* __restrict__ ce_mine,
                                             const int* __restrict__ num_pos,
                                             float* __restrict__ ce_t,
                                             const float* __restrict__ loss_l_t,
                                             const int* __restrict__ np_tot,
                                             unsigned* __restrict__ tick,
                                             float* __restrict__ out) {
    int b = blockIdx.x, tid = threadIdx.x;
    const float4* v4 = (const float4*)(ce_mine + (size_t)b * Pn);
    float4 r[8];
#pragma unroll
    for (int i = 0; i < 8; i++) r[i] = v4[i * 1024 + tid];

    int k = 3 * num_pos[b];
    if (k > Pn - 1) k = Pn - 1;

    __shared__ int hist[4][2048];             // 4-way sub-hist (per 4-wave group)
    __shared__ int wavetot[16];
    __shared__ int waveabove[16];
    __shared__ unsigned long long wcand[16];
    __shared__ unsigned s_lo;
    __shared__ int s_ab;
    __shared__ float ssum[16];
    __shared__ int   scnt[16];

    int lane = tid & 63, wv = tid >> 6;

    if (k > 0) {                              // uniform across block
        unsigned LO = 0u;
        int AB = 0;

        const int shifts[3] = {20, 9, 0};
        const int nbs[3]    = {2048, 2048, 512};

#pragma unroll
        for (int rd = 0; rd < 3; rd++) {
            int shift = shifts[rd], nb = nbs[rd];
            int* hf = &hist[0][0];
            for (int i = tid; i < 4 * 2048; i += 1024) hf[i] = 0;
            __syncthreads();
            int* myh = hist[wv >> 2];
#pragma unroll
            for (int i = 0; i < 8; i++) {
                float4 rv = r[i];
                float vals[4] = {rv.x, rv.y, rv.z, rv.w};
#pragma unroll
                for (int q = 0; q < 4; q++) {
                    unsigned u = __float_as_uint(vals[q]);
                    unsigned bin = (u - LO) >> shift;        // underflow -> huge -> skipped
                    if (bin < (unsigned)nb) atomicAdd(&myh[bin], 1);
                }
            }
            __syncthreads();
            int c0 = hist[0][2*tid] + hist[1][2*tid] + hist[2][2*tid] + hist[3][2*tid];
            int c1 = hist[0][2*tid+1] + hist[1][2*tid+1] + hist[2][2*tid+1] + hist[3][2*tid+1];
            int local = c0 + c1;
            int suf = local;
#pragma unroll
            for (int off = 1; off < 64; off <<= 1) {
                int src = lane + off;
                int o = __shfl(suf, src & 63, 64);
                suf += (src < 64) ? o : 0;
            }
            if (lane == 0) wavetot[wv] = suf;
            __syncthreads();
            if (tid == 0) {
                int acc = AB;                 // count(u >= bracket top)
                for (int w = 15; w >= 0; w--) { waveabove[w] = acc; acc += wavetot[w]; }
            }
            __syncthreads();
            int S0 = waveabove[wv] + suf;     // count(u >= LO + (2*tid)<<shift)
            int S1 = S0 - c0;                 // count(u >= LO + (2*tid+1)<<shift)
            int cand = -1; unsigned nab = 0;
            if (S0 >= k) { cand = 2*tid;     nab = (unsigned)(S0 - c0); }
            if (S1 >= k) { cand = 2*tid + 1; nab = (unsigned)(S1 - c1); }
            unsigned long long pk = ((unsigned long long)(unsigned)(cand + 1) << 32) | nab;
#pragma unroll
            for (int off = 32; off > 0; off >>= 1) {
                unsigned long long o = shfl_down_u64(pk, off);
                if (o > pk) pk = o;
            }
            if (lane == 0) wcand[wv] = pk;
            __syncthreads();
            if (tid == 0) {
                unsigned long long best = 0;
                for (int w = 0; w < 16; w++) if (wcand[w] > best) best = wcand[w];
                int ci = (int)(best >> 32) - 1;   // S_0 >= k guarantees ci >= 0
                s_lo = LO + ((unsigned)ci << shift);
                s_ab = (int)(best & 0xFFFFFFFFu);
            }
            __syncthreads();
            LO = s_lo; AB = s_ab;
        }
        // final bracket width 1: tau bits == LO; count(> tau) = AB < k <= count(>= tau)
        float tau = __uint_as_float(LO);
        float s = 0.f; int c = 0;
#pragma unroll
        for (int i = 0; i < 8; i++) {
            if (r[i].x > tau) { s += r[i].x; c++; }
            if (r[i].y > tau) { s += r[i].y; c++; }
            if (r[i].z > tau) { s += r[i].z; c++; }
            if (r[i].w > tau) { s += r[i].w; c++; }
        }
#pragma unroll
        for (int off = 32; off > 0; off >>= 1) {
            s += __shfl_down(s, off, 64);
            c += __shfl_down(c, off, 64);
        }
        if (lane == 0) { ssum[wv] = s; scnt[wv] = c; }
        __syncthreads();
        if (tid == 0) {
            float st = 0.f; int ct = 0;
            for (int w = 0; w < 16; w++) { st += ssum[w]; ct += scnt[w]; }
            atomicAdd(ce_t, st + (float)(k - ct) * tau);   // ties at tau, tie-agnostic exact
        }
    }

    // ticket: last block finalizes (device-scope atomics; adds happen-before ticket)
    if (tid == 0) {
        __threadfence();
        unsigned done = atomicAdd(tick, 1u);
        if (done == (unsigned)(Bn - 1)) {
            float N  = (float)atomicAdd((int*)np_tot, 0);
            float ll = atomicAdd((float*)loss_l_t, 0.f);
            float ce = atomicAdd(ce_t, 0.f);
            out[0] = ll / N;
            out[1] = ce / N;
        }
    }
}

extern "C" void kernel_launch(void* const* d_in, const int* in_sizes, int n_in,
                              void* d_out, int out_size, void* d_ws, size_t ws_size,
                              hipStream_t stream) {
    const float* loc     = (const float*)d_in[0];  // (B,P,3)
    const float* conf    = (const float*)d_in[1];  // (B,P,2)
    const float* priors  = (const float*)d_in[2];  // (P,4)
    const float* targets = (const float*)d_in[3];  // (B,O,5)
    float* out = (float*)d_out;

    char* ws = (char*)d_ws;
    unsigned long long* bpm = (unsigned long long*)ws;
    int*   num_pos  = (int*)(ws + 8192);
    float* loss_l_t = (float*)(ws + 8320);
    float* ce_t     = (float*)(ws + 8324);
    int*   np_tot   = (int*)(ws + 8328);
    unsigned* tick  = (unsigned*)(ws + 8332);
    float* ce_mine  = (float*)(ws + 16384);

    hipMemsetAsync(ws, 0, 16384, stream);

    hipLaunchKernelGGL(matchA, dim3((Bn * On) / AG, Pn / AC), dim3(256), 0, stream,
                       (const float4*)priors, targets, bpm);
    hipLaunchKernelGGL(matchB, dim3(Pn / BP, Bn), dim3(256), 0, stream,
                       loc, (const float2*)conf, (const float4*)priors, targets, bpm,
                       ce_mine, num_pos, loss_l_t, ce_t, np_tot);
    hipLaunchKernelGGL(topk, dim3(Bn), dim3(1024), 0, stream,
                       ce_mine, num_pos, ce_t, loss_l_t, np_tot, tick, out);
}